// Round 8
// baseline (820.071 us; speedup 1.0000x reference)
//
#include <hip/hip_runtime.h>

#define Bb 8
#define Nn 8192
#define Hh 256
#define NUP 2048
#define NDOWN (Nn - NUP)
#define MM 5
#define EPB (NDOWN * MM)   // edges per batch = 30720
#define NCELL 128
#define KP 288             // padded K for the feat GEMM (256 h + sl,score,1,pad)
#define LDA 36             // LDS row stride (bf16) for A/B tiles

typedef short v8s __attribute__((ext_vector_type(8)));
typedef float v4f __attribute__((ext_vector_type(4)));

// fp32 -> bf16 round-to-nearest-even
__device__ __forceinline__ unsigned short bfc(float f) {
    unsigned u = __float_as_uint(f);
    return (unsigned short)((u + 0x7FFFu + ((u >> 16) & 1u)) >> 16);
}

// Find the bin (descending order) where the kth-largest element lands.
template <int NB>
__device__ void find_kth_bin(const int* hist, int kth, int tid,
                             int* wsumA, int* res, int* out_bin, int* out_cntgt) {
    constexpr int PER = NB / 1024;
    int ln = tid & 63, wv = tid >> 6;
    int b0 = NB - 1 - PER * tid;
    int c0 = hist[b0];
    int c1 = (PER == 2) ? hist[b0 - 1] : 0;
    int tot = c0 + c1;
    int x = tot;
    #pragma unroll
    for (int off = 1; off < 64; off <<= 1) {
        int y = __shfl_up(x, off);
        if (ln >= off) x += y;
    }
    if (ln == 63) wsumA[wv] = x;
    __syncthreads();
    int wbase = 0;
    for (int w = 0; w < wv; w++) wbase += wsumA[w];
    int excl = wbase + x - tot;
    if (excl < kth && excl + c0 >= kth) { res[0] = b0; res[1] = excl; }
    else if (PER == 2 && excl + c0 < kth && excl + c0 + c1 >= kth) { res[0] = b0 - 1; res[1] = excl + c0; }
    __syncthreads();
    *out_bin = res[0];
    *out_cntgt = res[1];
}

// Kernel A: exact top-NUP selection via 3-level radix select, fused compaction
// + up_local inverse map + deg zeroing.
__global__ __launch_bounds__(1024) void select_kernel(
        const float* __restrict__ scores, const float* __restrict__ sl,
        int* __restrict__ mask, float4* __restrict__ upc,
        int* __restrict__ up_local, int* __restrict__ deg) {
    int b = blockIdx.x;
    int tid = threadIdx.x;
    int ln = tid & 63, wv = tid >> 6;
    __shared__ int hist[2048];
    __shared__ int wsumA[16], wsumB[16];
    __shared__ int res[2];
    __shared__ int sbase[2];
    const float* s = scores + (size_t)b * Nn;

    deg[b * NUP + tid] = 0;
    deg[b * NUP + 1024 + tid] = 0;

    hist[tid] = 0; hist[tid + 1024] = 0;
    __syncthreads();
    for (int t = tid; t < Nn; t += 1024)
        atomicAdd(&hist[__float_as_uint(s[t]) >> 21], 1);
    __syncthreads();
    int B1, gt1;
    find_kth_bin<2048>(hist, NUP, tid, wsumA, res, &B1, &gt1);
    int slots1 = NUP - gt1;

    hist[tid] = 0; hist[tid + 1024] = 0;
    __syncthreads();
    for (int t = tid; t < Nn; t += 1024) {
        unsigned u = __float_as_uint(s[t]);
        if ((int)(u >> 21) == B1) atomicAdd(&hist[(u >> 10) & 0x7FF], 1);
    }
    __syncthreads();
    int B2, gt2;
    find_kth_bin<2048>(hist, slots1, tid, wsumA, res, &B2, &gt2);
    int slots2 = slots1 - gt2;
    unsigned hi22 = ((unsigned)B1 << 11) | (unsigned)B2;

    hist[tid] = 0; hist[tid + 1024] = 0;
    __syncthreads();
    for (int t = tid; t < Nn; t += 1024) {
        unsigned u = __float_as_uint(s[t]);
        if ((u >> 10) == hi22) atomicAdd(&hist[u & 0x3FF], 1);
    }
    __syncthreads();
    int B3, gt3;
    find_kth_bin<1024>(hist, slots2, tid, wsumA, res, &B3, &gt3);
    int slots_eq = slots2 - gt3;
    unsigned T = (hi22 << 10) | (unsigned)B3;

    if (tid == 0) { sbase[0] = 0; sbase[1] = 0; }
    __syncthreads();
    for (int t0 = 0; t0 < Nn; t0 += 1024) {
        int node = t0 + tid;
        int g = b * Nn + node;
        unsigned u = __float_as_uint(s[node]);
        bool eq = (u == T);
        unsigned long long bal = __ballot(eq);
        unsigned long long lmask = (1ull << ln) - 1ull;
        int pre = __popcll(bal & lmask);
        if (ln == 0) wsumA[wv] = __popcll(bal);
        __syncthreads();
        int eqbase = sbase[0];
        for (int w = 0; w < wv; w++) eqbase += wsumA[w];
        bool up = (u > T) || (eq && (eqbase + pre) < slots_eq);
        unsigned long long bal2 = __ballot(up);
        int pre2 = __popcll(bal2 & lmask);
        if (ln == 0) wsumB[wv] = __popcll(bal2);
        __syncthreads();
        int upbase = sbase[1];
        for (int w = 0; w < wv; w++) upbase += wsumB[w];
        if (up) {
            float4 c;
            c.x = sl[(size_t)g * 3 + 0];
            c.y = sl[(size_t)g * 3 + 1];
            c.z = sl[(size_t)g * 3 + 2];
            c.w = __int_as_float(node);
            upc[b * NUP + upbase + pre2] = c;
            up_local[g] = upbase + pre2;
        }
        mask[g] = up ? 1 : 0;
        __syncthreads();
        if (tid == 0) {
            int se = 0, su = 0;
            for (int w = 0; w < 16; w++) { se += wsumA[w]; su += wsumB[w]; }
            sbase[0] += se; sbase[1] += su;
        }
        __syncthreads();
    }
}

// Kernel P: per-batch spatial prep. (1) bucket up points into NCELL x-cells
// (counting sort -> upg + cellptr + {xmin,w}); (2) counting-sort down nodes by
// home cell -> dord (wave-coherent processing order for knn_win).
__global__ __launch_bounds__(1024) void prep_kernel(
        const float* __restrict__ sl, const int* __restrict__ mask,
        const float4* __restrict__ upc, float4* __restrict__ upg,
        int* __restrict__ cellptr, float2* __restrict__ gridp,
        float4* __restrict__ dord) {
    int b = blockIdx.x;
    int tid = threadIdx.x;
    int ln = tid & 63, wv = tid >> 6;
    __shared__ float rmin[16], rmax[16];
    __shared__ int hist[NCELL], cur[NCELL];
    __shared__ int cp[NCELL + 1];
    __shared__ float sxmin, sw;

    float4 u0 = upc[b * NUP + tid];
    float4 u1 = upc[b * NUP + 1024 + tid];
    float mn = fminf(u0.x, u1.x), mx = fmaxf(u0.x, u1.x);
    #pragma unroll
    for (int off = 32; off; off >>= 1) {
        mn = fminf(mn, __shfl_down(mn, off));
        mx = fmaxf(mx, __shfl_down(mx, off));
    }
    if (ln == 0) { rmin[wv] = mn; rmax[wv] = mx; }
    if (tid < NCELL) hist[tid] = 0;
    __syncthreads();
    if (tid == 0) {
        float a = rmin[0], c = rmax[0];
        for (int w2 = 1; w2 < 16; w2++) { a = fminf(a, rmin[w2]); c = fmaxf(c, rmax[w2]); }
        float range = fmaxf(c - a, 1e-20f);
        sxmin = a;
        sw = range * (1.0f / NCELL) * 1.0000002f;  // inflate so x==xmax maps to NCELL-1
    }
    __syncthreads();
    float xmin = sxmin, w = sw;
    int ce0 = min(NCELL - 1, max(0, (int)((u0.x - xmin) / w)));
    int ce1 = min(NCELL - 1, max(0, (int)((u1.x - xmin) / w)));
    atomicAdd(&hist[ce0], 1);
    atomicAdd(&hist[ce1], 1);
    __syncthreads();
    if (wv == 0) {  // 64 lanes scan 128 bins (2 each)
        int a = hist[2 * ln], b2 = hist[2 * ln + 1];
        int s = a + b2; int x = s;
        #pragma unroll
        for (int off = 1; off < 64; off <<= 1) {
            int y = __shfl_up(x, off);
            if (ln >= off) x += y;
        }
        int excl = x - s;
        cp[2 * ln] = excl; cp[2 * ln + 1] = excl + a;
        if (ln == 63) cp[NCELL] = x;
    }
    __syncthreads();
    if (tid < NCELL) cur[tid] = cp[tid];
    if (tid <= NCELL) cellptr[b * (NCELL + 1) + tid] = cp[tid];
    if (tid == 0) gridp[b] = make_float2(xmin, w);
    __syncthreads();
    int s0 = atomicAdd(&cur[ce0], 1); upg[b * NUP + s0] = u0;
    int s1 = atomicAdd(&cur[ce1], 1); upg[b * NUP + s1] = u1;

    // ---- downs: counting-sort by home cell
    __syncthreads();
    if (tid < NCELL) hist[tid] = 0;
    __syncthreads();
    for (int t = tid; t < Nn; t += 1024) {
        int g = b * Nn + t;
        if (!mask[g]) {
            float x = sl[(size_t)g * 3 + 0];
            int c = min(NCELL - 1, max(0, (int)((x - xmin) / w)));
            atomicAdd(&hist[c], 1);
        }
    }
    __syncthreads();
    if (wv == 0) {
        int a = hist[2 * ln], b2 = hist[2 * ln + 1];
        int s = a + b2; int x = s;
        #pragma unroll
        for (int off = 1; off < 64; off <<= 1) {
            int y = __shfl_up(x, off);
            if (ln >= off) x += y;
        }
        int excl = x - s;
        cp[2 * ln] = excl; cp[2 * ln + 1] = excl + a;
    }
    __syncthreads();
    if (tid < NCELL) cur[tid] = cp[tid];
    __syncthreads();
    for (int t = tid; t < Nn; t += 1024) {
        int g = b * Nn + t;
        if (!mask[g]) {
            float x = sl[(size_t)g * 3 + 0];
            float y = sl[(size_t)g * 3 + 1];
            float z = sl[(size_t)g * 3 + 2];
            int c = min(NCELL - 1, max(0, (int)((x - xmin) / w)));
            int slot = atomicAdd(&cur[c], 1);
            float4 e; e.x = x; e.y = y; e.z = z; e.w = __int_as_float(t);
            dord[b * NDOWN + slot] = e;
        }
    }
}

// Kernel C: exact 5-NN via expanding x-cell walk. One wave per 64 down nodes
// (cell-sorted -> coherent lanes). A side deactivates only when its next
// cell's edge-distance^2 exceeds the current 5th-best -> exact. Inserts use
// packed u64 (d2bits<<32 | node_id) = exact (d2, idx) lex tie-break.
// Epilogue: write knn + fused in-degree count.
__global__ __launch_bounds__(64) void knn_win(
        const float4* __restrict__ upg, const int* __restrict__ cellptr,
        const float2* __restrict__ gridp, const float4* __restrict__ dord,
        const int* __restrict__ up_local, int* __restrict__ knn,
        int* __restrict__ deg) {
    int b = blockIdx.y;
    int lane = threadIdx.x;
    __shared__ float4 S[NUP];
    __shared__ int cp[NCELL + 1];
    for (int k = lane; k < NUP; k += 64) S[k] = upg[b * NUP + k];
    for (int k = lane; k <= NCELL; k += 64) cp[k] = cellptr[b * (NCELL + 1) + k];
    __syncthreads();
    float2 gw = gridp[b];
    float xmin = gw.x, w = gw.y;
    float4 d = dord[b * NDOWN + blockIdx.x * 64 + lane];
    float xd = d.x, yd = d.y, zd = d.z;
    int node = __float_as_int(d.w);
    int c0 = min(NCELL - 1, max(0, (int)((xd - xmin) / w)));

    unsigned long long bd[MM];
    #pragma unroll
    for (int m = 0; m < MM; m++) bd[m] = 0x7F800000FFFFFFFFull;
    float Tf = __uint_as_float(0x7F800000u);  // +inf

    int cR = c0, pR = cp[c0], eR = cp[c0 + 1];
    bool actR = true;
    float bndR = 0.f;
    int cL = c0, pL = 0, bL = 0;
    bool actL = true;
    float bndL = 0.f;

    auto advR = [&]() {
        while (true) {
            cR++;
            if (cR >= NCELL) { actR = false; break; }
            float bn = fmaxf(0.f, (xmin + cR * w) - xd);
            if (bn * bn > Tf) { actR = false; break; }
            pR = cp[cR]; eR = cp[cR + 1]; bndR = bn;
            if (pR < eR) break;
        }
    };
    auto advL = [&]() {
        while (true) {
            cL--;
            if (cL < 0) { actL = false; break; }
            float bn = fmaxf(0.f, xd - (xmin + (cL + 1) * w));
            if (bn * bn > Tf) { actL = false; break; }
            pL = cp[cL + 1] - 1; bL = cp[cL]; bndL = bn;
            if (pL >= bL) break;
        }
    };
    if (pR >= eR) advR();   // empty home cell
    advL();                 // left starts at cell c0-1

    while (__ballot(actR || actL)) {
        bool act = actR || actL;
        if (act) {
            bool useR = actR && (!actL || bndR <= bndL);
            int p = useR ? pR : pL;
            float4 c = S[p];
            float dx = c.x - xd, dy = c.y - yd, dz = c.z - zd;
            float d2 = fmaf(dx, dx, fmaf(dy, dy, dz * dz));
            unsigned long long cand =
                ((unsigned long long)__float_as_uint(d2) << 32) |
                (unsigned long long)(unsigned)__float_as_int(c.w);
            #pragma unroll
            for (int m = 0; m < MM; m++) {
                bool lt = cand < bd[m];
                unsigned long long lo = lt ? cand : bd[m];
                unsigned long long hi = lt ? bd[m] : cand;
                bd[m] = lo; cand = hi;
            }
            Tf = __uint_as_float((unsigned)(bd[MM - 1] >> 32));
            if (useR) { pR++; if (pR >= eR) advR(); }
            else      { pL--; if (pL < bL) advL(); }
        }
    }

    int g = b * Nn + node;
    #pragma unroll
    for (int m = 0; m < MM; m++) {
        int nid = (int)(unsigned)(bd[m] & 0xFFFFFFFFull);
        knn[g * MM + m] = nid;
        atomicAdd(&deg[b * NUP + up_local[b * Nn + nid]], 1);
    }
}

// Kernel W: Wt[n][k] = bf16 of W-ext^T.
__global__ void wt_kernel(const float* __restrict__ W, const float* __restrict__ bias,
                          unsigned short* __restrict__ Wt) {
    int n = blockIdx.x;
    int k = threadIdx.x;
    Wt[n * KP + k] = bfc(W[(size_t)k * Hh + n]);
    if (k < KP - 256) {
        int kk = 256 + k;
        unsigned short v = 0;
        if (kk < 260)       v = bfc(W[(size_t)kk * Hh + n]);
        else if (kk == 260) v = bfc(bias[n]);
        Wt[n * KP + kk] = v;
    }
}

// Kernel B: feat GEMM via bf16 MFMA. C[128m x 128n] per block, 4 waves of 64x64.
__global__ void feat_mfma(const float* __restrict__ h, const float* __restrict__ sl,
                          const float* __restrict__ sc, const unsigned short* __restrict__ Wt,
                          float* __restrict__ out) {
    int b = blockIdx.z;
    int m0 = blockIdx.x * 128;
    int n0 = blockIdx.y * 128;
    int tid = threadIdx.x;
    __shared__ unsigned short Al[128 * LDA];
    __shared__ unsigned short Bl[128 * LDA];
    int wid = tid >> 6, lane = tid & 63;
    int wm = (wid & 1) * 64, wn = (wid >> 1) * 64;
    int lm = lane & 15, quad = lane >> 4;
    v4f acc[4][4];
    #pragma unroll
    for (int i = 0; i < 4; i++)
        #pragma unroll
        for (int j = 0; j < 4; j++)
            acc[i][j] = (v4f){0.f, 0.f, 0.f, 0.f};
    const float* Ab = h + ((size_t)b * Nn + m0) * Hh;
    for (int t = 0; t < 9; t++) {
        int k0 = t * 32;
        __syncthreads();
        if (t < 8) {
            #pragma unroll
            for (int q = 0; q < 4; q++) {
                int e = q * 256 + tid;
                int row = e >> 3, kq = e & 7;
                float4 v = *(const float4*)(Ab + (size_t)row * Hh + k0 + kq * 4);
                ushort4 o = make_ushort4(bfc(v.x), bfc(v.y), bfc(v.z), bfc(v.w));
                *(ushort4*)(Al + row * LDA + kq * 4) = o;
            }
        } else if (tid < 128) {
            int row = tid;
            int g = b * Nn + m0 + row;
            unsigned short r[32];
            #pragma unroll
            for (int k = 0; k < 32; k++) r[k] = 0;
            r[0] = bfc(sl[(size_t)g * 3 + 0]);
            r[1] = bfc(sl[(size_t)g * 3 + 1]);
            r[2] = bfc(sl[(size_t)g * 3 + 2]);
            r[3] = bfc(sc[g]);
            r[4] = 0x3F80;  // 1.0 (bias column)
            #pragma unroll
            for (int q = 0; q < 8; q++)
                *(ushort4*)(Al + row * LDA + q * 4) =
                    make_ushort4(r[q * 4], r[q * 4 + 1], r[q * 4 + 2], r[q * 4 + 3]);
        }
        #pragma unroll
        for (int q = 0; q < 4; q++) {
            int e = q * 256 + tid;
            int n = e >> 3, kq = e & 7;
            ushort4 v = *(const ushort4*)(Wt + (size_t)(n0 + n) * KP + k0 + kq * 4);
            *(ushort4*)(Bl + n * LDA + kq * 4) = v;
        }
        __syncthreads();
        v8s af[4], bfr[4];
        #pragma unroll
        for (int i = 0; i < 4; i++)
            af[i] = *(const v8s*)(Al + (wm + i * 16 + lm) * LDA + quad * 8);
        #pragma unroll
        for (int j = 0; j < 4; j++)
            bfr[j] = *(const v8s*)(Bl + (wn + j * 16 + lm) * LDA + quad * 8);
        #pragma unroll
        for (int i = 0; i < 4; i++)
            #pragma unroll
            for (int j = 0; j < 4; j++)
                acc[i][j] = __builtin_amdgcn_mfma_f32_16x16x32_bf16(af[i], bfr[j], acc[i][j], 0, 0, 0);
    }
    #pragma unroll
    for (int i = 0; i < 4; i++) {
        #pragma unroll
        for (int r = 0; r < 4; r++) {
            int row = m0 + wm + i * 16 + quad * 4 + r;
            size_t base = ((size_t)b * Nn + row) * Hh + n0 + wn + lm;
            #pragma unroll
            for (int j = 0; j < 4; j++)
                out[base + j * 16] = acc[i][j][r];
        }
    }
}

// CSR build: per-batch exclusive scan of deg -> rowptr (+ cursor copy).
__global__ __launch_bounds__(1024) void csr_scan(const int* __restrict__ deg,
                                                 int* __restrict__ rowptr,
                                                 int* __restrict__ cursor) {
    int b = blockIdx.x;
    int tid = threadIdx.x;
    int ln = tid & 63, wv = tid >> 6;
    __shared__ int wsum[16];
    int d0 = deg[b * NUP + 2 * tid], d1 = deg[b * NUP + 2 * tid + 1];
    int s = d0 + d1;
    int x = s;
    #pragma unroll
    for (int off = 1; off < 64; off <<= 1) {
        int y = __shfl_up(x, off);
        if (ln >= off) x += y;
    }
    if (ln == 63) wsum[wv] = x;
    __syncthreads();
    int base = 0;
    for (int w = 0; w < wv; w++) base += wsum[w];
    int excl = base + x - s;
    rowptr[b * (NUP + 1) + 2 * tid] = excl;
    rowptr[b * (NUP + 1) + 2 * tid + 1] = excl + d0;
    cursor[b * NUP + 2 * tid] = excl;
    cursor[b * NUP + 2 * tid + 1] = excl + d0;
    if (tid == 1023) rowptr[b * (NUP + 1) + NUP] = excl + s;
}

// CSR build: fill edge array (src = batch-local down node id).
__global__ void csr_fill(const int* __restrict__ mask, const int* __restrict__ knn,
                         const int* __restrict__ up_local, int* __restrict__ cursor,
                         int* __restrict__ edges) {
    int b = blockIdx.y;
    int i = blockIdx.x * 256 + threadIdx.x;
    int g = b * Nn + i;
    if (mask[g]) return;
    #pragma unroll
    for (int m = 0; m < MM; m++) {
        int un = knn[g * MM + m];
        int slot = atomicAdd(&cursor[b * NUP + up_local[b * Nn + un]], 1);
        edges[b * EPB + slot] = i;
    }
}

// Kernel D: gather-max. One wave per up node; lanes own 4 cols (float4).
__global__ void gather_kernel(const float4* __restrict__ upc, const int* __restrict__ rowptr,
                              const int* __restrict__ edges, float* __restrict__ out) {
    int b = blockIdx.y;
    int u = blockIdx.x * 4 + (threadIdx.x >> 6);
    int lane = threadIdx.x & 63;
    int node = __float_as_int(upc[b * NUP + u].w);
    int start = rowptr[b * (NUP + 1) + u];
    int end   = rowptr[b * (NUP + 1) + u + 1];
    const int* eb = edges + b * EPB;
    size_t rowbase = (size_t)b * Nn * Hh + (size_t)(lane << 2);
    float4 a0 = make_float4(-3.4e38f, -3.4e38f, -3.4e38f, -3.4e38f);
    float4 a1 = a0;
    int e = start;
    for (; e + 2 <= end; e += 2) {
        int s0 = eb[e], s1 = eb[e + 1];
        float4 v0 = *(const float4*)(out + rowbase + (size_t)s0 * Hh);
        float4 v1 = *(const float4*)(out + rowbase + (size_t)s1 * Hh);
        a0.x = fmaxf(a0.x, v0.x); a0.y = fmaxf(a0.y, v0.y);
        a0.z = fmaxf(a0.z, v0.z); a0.w = fmaxf(a0.w, v0.w);
        a1.x = fmaxf(a1.x, v1.x); a1.y = fmaxf(a1.y, v1.y);
        a1.z = fmaxf(a1.z, v1.z); a1.w = fmaxf(a1.w, v1.w);
    }
    if (e < end) {
        int s0 = eb[e];
        float4 v0 = *(const float4*)(out + rowbase + (size_t)s0 * Hh);
        a0.x = fmaxf(a0.x, v0.x); a0.y = fmaxf(a0.y, v0.y);
        a0.z = fmaxf(a0.z, v0.z); a0.w = fmaxf(a0.w, v0.w);
    }
    float4 r;
    r.x = fmaxf(a0.x, a1.x); r.y = fmaxf(a0.y, a1.y);
    r.z = fmaxf(a0.z, a1.z); r.w = fmaxf(a0.w, a1.w);
    if (start == end) r = make_float4(0.f, 0.f, 0.f, 0.f);
    *(float4*)(out + rowbase + (size_t)node * Hh) = r;
}

// Kernel E: zero down rows, write mask tail.
__global__ void finalize_kernel(const int* __restrict__ mask, float* __restrict__ out) {
    int b = blockIdx.y;
    int node = blockIdx.x * 4 + (threadIdx.x >> 6);
    int g = b * Nn + node;
    int lane = threadIdx.x & 63;
    bool up = mask[g] != 0;
    if (!up)
        *(float4*)(out + (size_t)g * Hh + (lane << 2)) = make_float4(0.f, 0.f, 0.f, 0.f);
    if (lane == 0) out[(size_t)Bb * Nn * Hh + g] = up ? 1.0f : 0.0f;
}

extern "C" void kernel_launch(void* const* d_in, const int* in_sizes, int n_in,
                              void* d_out, int out_size, void* d_ws, size_t ws_size,
                              hipStream_t stream) {
    const float* h    = (const float*)d_in[0];
    const float* sl   = (const float*)d_in[1];
    const float* sc   = (const float*)d_in[2];
    const float* W    = (const float*)d_in[3];
    const float* bias = (const float*)d_in[4];

    char* ws = (char*)d_ws;
    int* mask = (int*)ws;                 ws += (size_t)Bb * Nn * sizeof(int);
    int* knn  = (int*)ws;                 ws += (size_t)Bb * Nn * MM * sizeof(int);
    float4* upc = (float4*)ws;            ws += (size_t)Bb * NUP * sizeof(float4);
    unsigned short* Wt = (unsigned short*)ws; ws += (size_t)Hh * KP * sizeof(unsigned short);
    int* up_local = (int*)ws;             ws += (size_t)Bb * Nn * sizeof(int);
    int* deg = (int*)ws;                  ws += (size_t)Bb * NUP * sizeof(int);
    int* cursor = (int*)ws;               ws += (size_t)Bb * NUP * sizeof(int);
    int* rowptr = (int*)ws;               ws += (size_t)Bb * (NUP + 1) * sizeof(int);
    int* edges = (int*)ws;                ws += (size_t)Bb * EPB * sizeof(int);
    float4* upg = (float4*)ws;            ws += (size_t)Bb * NUP * sizeof(float4);
    int* cellptr = (int*)ws;              ws += (size_t)Bb * (NCELL + 1) * sizeof(int);
    float2* gridp = (float2*)ws;          ws += (size_t)Bb * sizeof(float2);
    float4* dord = (float4*)ws;           // B*NDOWN float4
    float* outf = (float*)d_out;

    dim3 blk(256);
    select_kernel<<<dim3(Bb), dim3(1024), 0, stream>>>(sc, sl, mask, upc, up_local, deg);
    prep_kernel<<<dim3(Bb), dim3(1024), 0, stream>>>(sl, mask, upc, upg, cellptr, gridp, dord);
    knn_win<<<dim3(NDOWN / 64, Bb), dim3(64), 0, stream>>>(upg, cellptr, gridp, dord,
                                                           up_local, knn, deg);
    csr_scan<<<dim3(Bb), dim3(1024), 0, stream>>>(deg, rowptr, cursor);
    csr_fill<<<dim3(Nn / 256, Bb), blk, 0, stream>>>(mask, knn, up_local, cursor, edges);
    wt_kernel<<<dim3(Hh), blk, 0, stream>>>(W, bias, Wt);
    feat_mfma<<<dim3(Nn / 128, 2, Bb), blk, 0, stream>>>(h, sl, sc, Wt, outf);
    gather_kernel<<<dim3(NUP / 4, Bb), blk, 0, stream>>>(upc, rowptr, edges, outf);
    finalize_kernel<<<dim3(Nn / 4, Bb), blk, 0, stream>>>(mask, outf);
}

// Round 9
// 484.047 us; speedup vs baseline: 1.6942x; 1.6942x over previous
//
#include <hip/hip_runtime.h>

#define Bb 8
#define Nn 8192
#define Hh 256
#define NUP 2048
#define NDOWN (Nn - NUP)
#define MM 5
#define EPB (NDOWN * MM)   // edges per batch = 30720
#define NCELL 128
#define KP 288             // padded K for the feat GEMM (256 h + sl,score,1,pad)
#define LDA 36             // LDS row stride (bf16) for A/B tiles

typedef short v8s __attribute__((ext_vector_type(8)));
typedef float v4f __attribute__((ext_vector_type(4)));

// fp32 -> bf16 round-to-nearest-even
__device__ __forceinline__ unsigned short bfc(float f) {
    unsigned u = __float_as_uint(f);
    return (unsigned short)((u + 0x7FFFu + ((u >> 16) & 1u)) >> 16);
}

// Find the bin (descending order) where the kth-largest element lands.
template <int NB>
__device__ void find_kth_bin(const int* hist, int kth, int tid,
                             int* wsumA, int* res, int* out_bin, int* out_cntgt) {
    constexpr int PER = NB / 1024;
    int ln = tid & 63, wv = tid >> 6;
    int b0 = NB - 1 - PER * tid;
    int c0 = hist[b0];
    int c1 = (PER == 2) ? hist[b0 - 1] : 0;
    int tot = c0 + c1;
    int x = tot;
    #pragma unroll
    for (int off = 1; off < 64; off <<= 1) {
        int y = __shfl_up(x, off);
        if (ln >= off) x += y;
    }
    if (ln == 63) wsumA[wv] = x;
    __syncthreads();
    int wbase = 0;
    for (int w = 0; w < wv; w++) wbase += wsumA[w];
    int excl = wbase + x - tot;
    if (excl < kth && excl + c0 >= kth) { res[0] = b0; res[1] = excl; }
    else if (PER == 2 && excl + c0 < kth && excl + c0 + c1 >= kth) { res[0] = b0 - 1; res[1] = excl + c0; }
    __syncthreads();
    *out_bin = res[0];
    *out_cntgt = res[1];
}

// Kernel A: exact top-NUP selection via 3-level radix select, fused compaction
// + up_local inverse map + deg zeroing.
__global__ __launch_bounds__(1024) void select_kernel(
        const float* __restrict__ scores, const float* __restrict__ sl,
        int* __restrict__ mask, float4* __restrict__ upc,
        int* __restrict__ up_local, int* __restrict__ deg) {
    int b = blockIdx.x;
    int tid = threadIdx.x;
    int ln = tid & 63, wv = tid >> 6;
    __shared__ int hist[2048];
    __shared__ int wsumA[16], wsumB[16];
    __shared__ int res[2];
    __shared__ int sbase[2];
    const float* s = scores + (size_t)b * Nn;

    deg[b * NUP + tid] = 0;
    deg[b * NUP + 1024 + tid] = 0;

    hist[tid] = 0; hist[tid + 1024] = 0;
    __syncthreads();
    for (int t = tid; t < Nn; t += 1024)
        atomicAdd(&hist[__float_as_uint(s[t]) >> 21], 1);
    __syncthreads();
    int B1, gt1;
    find_kth_bin<2048>(hist, NUP, tid, wsumA, res, &B1, &gt1);
    int slots1 = NUP - gt1;

    hist[tid] = 0; hist[tid + 1024] = 0;
    __syncthreads();
    for (int t = tid; t < Nn; t += 1024) {
        unsigned u = __float_as_uint(s[t]);
        if ((int)(u >> 21) == B1) atomicAdd(&hist[(u >> 10) & 0x7FF], 1);
    }
    __syncthreads();
    int B2, gt2;
    find_kth_bin<2048>(hist, slots1, tid, wsumA, res, &B2, &gt2);
    int slots2 = slots1 - gt2;
    unsigned hi22 = ((unsigned)B1 << 11) | (unsigned)B2;

    hist[tid] = 0; hist[tid + 1024] = 0;
    __syncthreads();
    for (int t = tid; t < Nn; t += 1024) {
        unsigned u = __float_as_uint(s[t]);
        if ((u >> 10) == hi22) atomicAdd(&hist[u & 0x3FF], 1);
    }
    __syncthreads();
    int B3, gt3;
    find_kth_bin<1024>(hist, slots2, tid, wsumA, res, &B3, &gt3);
    int slots_eq = slots2 - gt3;
    unsigned T = (hi22 << 10) | (unsigned)B3;

    if (tid == 0) { sbase[0] = 0; sbase[1] = 0; }
    __syncthreads();
    for (int t0 = 0; t0 < Nn; t0 += 1024) {
        int node = t0 + tid;
        int g = b * Nn + node;
        unsigned u = __float_as_uint(s[node]);
        bool eq = (u == T);
        unsigned long long bal = __ballot(eq);
        unsigned long long lmask = (1ull << ln) - 1ull;
        int pre = __popcll(bal & lmask);
        if (ln == 0) wsumA[wv] = __popcll(bal);
        __syncthreads();
        int eqbase = sbase[0];
        for (int w = 0; w < wv; w++) eqbase += wsumA[w];
        bool up = (u > T) || (eq && (eqbase + pre) < slots_eq);
        unsigned long long bal2 = __ballot(up);
        int pre2 = __popcll(bal2 & lmask);
        if (ln == 0) wsumB[wv] = __popcll(bal2);
        __syncthreads();
        int upbase = sbase[1];
        for (int w = 0; w < wv; w++) upbase += wsumB[w];
        if (up) {
            float4 c;
            c.x = sl[(size_t)g * 3 + 0];
            c.y = sl[(size_t)g * 3 + 1];
            c.z = sl[(size_t)g * 3 + 2];
            c.w = __int_as_float(node);
            upc[b * NUP + upbase + pre2] = c;
            up_local[g] = upbase + pre2;
        }
        mask[g] = up ? 1 : 0;
        __syncthreads();
        if (tid == 0) {
            int se = 0, su = 0;
            for (int w = 0; w < 16; w++) { se += wsumA[w]; su += wsumB[w]; }
            sbase[0] += se; sbase[1] += su;
        }
        __syncthreads();
    }
}

// Kernel P: per-batch spatial prep. (1) bucket up points into NCELL x-cells
// (counting sort -> upg + cellptr + {xmin,w}); (2) counting-sort down nodes by
// home cell -> dord (wave-coherent processing order for knn_wave).
__global__ __launch_bounds__(1024) void prep_kernel(
        const float* __restrict__ sl, const int* __restrict__ mask,
        const float4* __restrict__ upc, float4* __restrict__ upg,
        int* __restrict__ cellptr, float2* __restrict__ gridp,
        float4* __restrict__ dord) {
    int b = blockIdx.x;
    int tid = threadIdx.x;
    int ln = tid & 63, wv = tid >> 6;
    __shared__ float rmin[16], rmax[16];
    __shared__ int hist[NCELL], cur[NCELL];
    __shared__ int cp[NCELL + 1];
    __shared__ float sxmin, sw;

    float4 u0 = upc[b * NUP + tid];
    float4 u1 = upc[b * NUP + 1024 + tid];
    float mn = fminf(u0.x, u1.x), mx = fmaxf(u0.x, u1.x);
    #pragma unroll
    for (int off = 32; off; off >>= 1) {
        mn = fminf(mn, __shfl_down(mn, off));
        mx = fmaxf(mx, __shfl_down(mx, off));
    }
    if (ln == 0) { rmin[wv] = mn; rmax[wv] = mx; }
    if (tid < NCELL) hist[tid] = 0;
    __syncthreads();
    if (tid == 0) {
        float a = rmin[0], c = rmax[0];
        for (int w2 = 1; w2 < 16; w2++) { a = fminf(a, rmin[w2]); c = fmaxf(c, rmax[w2]); }
        float range = fmaxf(c - a, 1e-20f);
        sxmin = a;
        sw = range * (1.0f / NCELL) * 1.0000002f;  // inflate so x==xmax maps to NCELL-1
    }
    __syncthreads();
    float xmin = sxmin, w = sw;
    int ce0 = min(NCELL - 1, max(0, (int)((u0.x - xmin) / w)));
    int ce1 = min(NCELL - 1, max(0, (int)((u1.x - xmin) / w)));
    atomicAdd(&hist[ce0], 1);
    atomicAdd(&hist[ce1], 1);
    __syncthreads();
    if (wv == 0) {  // 64 lanes scan 128 bins (2 each)
        int a = hist[2 * ln], b2 = hist[2 * ln + 1];
        int s = a + b2; int x = s;
        #pragma unroll
        for (int off = 1; off < 64; off <<= 1) {
            int y = __shfl_up(x, off);
            if (ln >= off) x += y;
        }
        int excl = x - s;
        cp[2 * ln] = excl; cp[2 * ln + 1] = excl + a;
        if (ln == 63) cp[NCELL] = x;
    }
    __syncthreads();
    if (tid < NCELL) cur[tid] = cp[tid];
    if (tid <= NCELL) cellptr[b * (NCELL + 1) + tid] = cp[tid];
    if (tid == 0) gridp[b] = make_float2(xmin, w);
    __syncthreads();
    int s0 = atomicAdd(&cur[ce0], 1); upg[b * NUP + s0] = u0;
    int s1 = atomicAdd(&cur[ce1], 1); upg[b * NUP + s1] = u1;

    // ---- downs: counting-sort by home cell
    __syncthreads();
    if (tid < NCELL) hist[tid] = 0;
    __syncthreads();
    for (int t = tid; t < Nn; t += 1024) {
        int g = b * Nn + t;
        if (!mask[g]) {
            float x = sl[(size_t)g * 3 + 0];
            int c = min(NCELL - 1, max(0, (int)((x - xmin) / w)));
            atomicAdd(&hist[c], 1);
        }
    }
    __syncthreads();
    if (wv == 0) {
        int a = hist[2 * ln], b2 = hist[2 * ln + 1];
        int s = a + b2; int x = s;
        #pragma unroll
        for (int off = 1; off < 64; off <<= 1) {
            int y = __shfl_up(x, off);
            if (ln >= off) x += y;
        }
        int excl = x - s;
        cp[2 * ln] = excl; cp[2 * ln + 1] = excl + a;
    }
    __syncthreads();
    if (tid < NCELL) cur[tid] = cp[tid];
    __syncthreads();
    for (int t = tid; t < Nn; t += 1024) {
        int g = b * Nn + t;
        if (!mask[g]) {
            float x = sl[(size_t)g * 3 + 0];
            float y = sl[(size_t)g * 3 + 1];
            float z = sl[(size_t)g * 3 + 2];
            int c = min(NCELL - 1, max(0, (int)((x - xmin) / w)));
            int slot = atomicAdd(&cur[c], 1);
            float4 e; e.x = x; e.y = y; e.z = z; e.w = __int_as_float(t);
            dord[b * NDOWN + slot] = e;
        }
    }
}

// Kernel C: exact 5-NN, wave-shared expanding cell window, dense branchless
// inner loop. One 64-thread wave handles 64 cell-sorted downs; all lanes scan
// the SAME wave-uniform candidate stream (global broadcast loads, no LDS).
// A side stops only when its cell edge-dist^2 > wave-max upper bound of the
// per-lane 5th-best -> exact. u64 keys (d2bits<<32|id) = exact (d2,idx) ties.
// Epilogue: knn write + fused in-degree count.
__global__ __launch_bounds__(64) void knn_wave(
        const float4* __restrict__ upg, const int* __restrict__ cellptr,
        const float2* __restrict__ gridp, const float4* __restrict__ dord,
        const int* __restrict__ up_local, int* __restrict__ knn,
        int* __restrict__ deg) {
    int b = blockIdx.y;
    int lane = threadIdx.x;
    const float4* U = upg + b * NUP;
    const int* cp = cellptr + b * (NCELL + 1);
    float2 gw = gridp[b];
    float xmin = gw.x, w = gw.y;
    float4 d = dord[b * NDOWN + blockIdx.x * 64 + lane];
    float xd = d.x, yd = d.y, zd = d.z;
    int node = __float_as_int(d.w);

    // wave x-extent (downs are cell-sorted, not x-sorted within a cell)
    float xlo = xd, xhi = xd;
    #pragma unroll
    for (int off = 32; off; off >>= 1) {
        xlo = fminf(xlo, __shfl_xor(xlo, off));
        xhi = fmaxf(xhi, __shfl_xor(xhi, off));
    }
    int cLo = min(NCELL - 1, max(0, (int)((xlo - xmin) / w)));
    int cHi = min(NCELL - 1, max(0, (int)((xhi - xmin) / w)));

    unsigned long long bd[4][MM];
    #pragma unroll
    for (int l = 0; l < 4; l++)
        #pragma unroll
        for (int m = 0; m < MM; m++) bd[l][m] = 0x7F800000FFFFFFFFull;

    auto key = [&](float4 c) -> unsigned long long {
        float dx = c.x - xd, dy = c.y - yd, dz = c.z - zd;
        float d2 = fmaf(dx, dx, fmaf(dy, dy, dz * dz));
        return ((unsigned long long)__float_as_uint(d2) << 32) |
               (unsigned long long)(unsigned)__float_as_int(c.w);
    };
    auto ins = [&](unsigned long long* L, unsigned long long cand) {
        #pragma unroll
        for (int m = 0; m < MM; m++) {
            bool lt = cand < L[m];
            unsigned long long lo = lt ? cand : L[m];
            unsigned long long hi = lt ? L[m] : cand;
            L[m] = lo; cand = hi;
        }
    };
    auto process = [&](int ps, int pe) {
        int p = ps;
        for (; p + 4 <= pe; p += 4) {
            float4 c0 = U[p], c1 = U[p + 1], c2 = U[p + 2], c3 = U[p + 3];
            ins(bd[0], key(c0));
            ins(bd[1], key(c1));
            ins(bd[2], key(c2));
            ins(bd[3], key(c3));
        }
        for (; p < pe; p++) ins(bd[0], key(U[p]));
    };

    // home span first (covers every lane's home cell)
    process(cp[cLo], cp[cHi + 1]);
    int cR = cHi + 1, cL = cLo - 1;

    while (true) {
        // per-lane upper bound on true 5th-best: min over lists of their 5th
        unsigned t01 = min((unsigned)(bd[0][MM - 1] >> 32), (unsigned)(bd[1][MM - 1] >> 32));
        unsigned t23 = min((unsigned)(bd[2][MM - 1] >> 32), (unsigned)(bd[3][MM - 1] >> 32));
        float T = __uint_as_float(min(t01, t23));
        #pragma unroll
        for (int off = 32; off; off >>= 1)
            T = fmaxf(T, __shfl_xor(T, off));
        float bR = fmaxf(0.f, xmin + cR * w - xhi);
        float bL = fmaxf(0.f, xlo - (xmin + (cL + 1) * w));
        bool okR = (cR < NCELL) && (bR * bR <= T);
        bool okL = (cL >= 0) && (bL * bL <= T);
        if (!okR && !okL) break;
        int c;
        if (okR && (!okL || bR <= bL)) { c = cR; cR++; }
        else                           { c = cL; cL--; }
        process(cp[c], cp[c + 1]);
    }

    // merge 4 lists -> final top-5 (u64 total order, exact)
    unsigned long long fin[MM];
    #pragma unroll
    for (int m = 0; m < MM; m++) fin[m] = 0xFFFFFFFFFFFFFFFFull;
    #pragma unroll
    for (int l = 0; l < 4; l++)
        #pragma unroll
        for (int m = 0; m < MM; m++) ins(fin, bd[l][m]);

    int g = b * Nn + node;
    #pragma unroll
    for (int m = 0; m < MM; m++) {
        int nid = (int)(unsigned)(fin[m] & 0xFFFFFFFFull);
        knn[g * MM + m] = nid;
        atomicAdd(&deg[b * NUP + up_local[b * Nn + nid]], 1);
    }
}

// Kernel W: Wt[n][k] = bf16 of W-ext^T.
__global__ void wt_kernel(const float* __restrict__ W, const float* __restrict__ bias,
                          unsigned short* __restrict__ Wt) {
    int n = blockIdx.x;
    int k = threadIdx.x;
    Wt[n * KP + k] = bfc(W[(size_t)k * Hh + n]);
    if (k < KP - 256) {
        int kk = 256 + k;
        unsigned short v = 0;
        if (kk < 260)       v = bfc(W[(size_t)kk * Hh + n]);
        else if (kk == 260) v = bfc(bias[n]);
        Wt[n * KP + kk] = v;
    }
}

// Kernel B: feat GEMM via bf16 MFMA. C[128m x 128n] per block, 4 waves of 64x64.
__global__ void feat_mfma(const float* __restrict__ h, const float* __restrict__ sl,
                          const float* __restrict__ sc, const unsigned short* __restrict__ Wt,
                          float* __restrict__ out) {
    int b = blockIdx.z;
    int m0 = blockIdx.x * 128;
    int n0 = blockIdx.y * 128;
    int tid = threadIdx.x;
    __shared__ unsigned short Al[128 * LDA];
    __shared__ unsigned short Bl[128 * LDA];
    int wid = tid >> 6, lane = tid & 63;
    int wm = (wid & 1) * 64, wn = (wid >> 1) * 64;
    int lm = lane & 15, quad = lane >> 4;
    v4f acc[4][4];
    #pragma unroll
    for (int i = 0; i < 4; i++)
        #pragma unroll
        for (int j = 0; j < 4; j++)
            acc[i][j] = (v4f){0.f, 0.f, 0.f, 0.f};
    const float* Ab = h + ((size_t)b * Nn + m0) * Hh;
    for (int t = 0; t < 9; t++) {
        int k0 = t * 32;
        __syncthreads();
        if (t < 8) {
            #pragma unroll
            for (int q = 0; q < 4; q++) {
                int e = q * 256 + tid;
                int row = e >> 3, kq = e & 7;
                float4 v = *(const float4*)(Ab + (size_t)row * Hh + k0 + kq * 4);
                ushort4 o = make_ushort4(bfc(v.x), bfc(v.y), bfc(v.z), bfc(v.w));
                *(ushort4*)(Al + row * LDA + kq * 4) = o;
            }
        } else if (tid < 128) {
            int row = tid;
            int g = b * Nn + m0 + row;
            unsigned short r[32];
            #pragma unroll
            for (int k = 0; k < 32; k++) r[k] = 0;
            r[0] = bfc(sl[(size_t)g * 3 + 0]);
            r[1] = bfc(sl[(size_t)g * 3 + 1]);
            r[2] = bfc(sl[(size_t)g * 3 + 2]);
            r[3] = bfc(sc[g]);
            r[4] = 0x3F80;  // 1.0 (bias column)
            #pragma unroll
            for (int q = 0; q < 8; q++)
                *(ushort4*)(Al + row * LDA + q * 4) =
                    make_ushort4(r[q * 4], r[q * 4 + 1], r[q * 4 + 2], r[q * 4 + 3]);
        }
        #pragma unroll
        for (int q = 0; q < 4; q++) {
            int e = q * 256 + tid;
            int n = e >> 3, kq = e & 7;
            ushort4 v = *(const ushort4*)(Wt + (size_t)(n0 + n) * KP + k0 + kq * 4);
            *(ushort4*)(Bl + n * LDA + kq * 4) = v;
        }
        __syncthreads();
        v8s af[4], bfr[4];
        #pragma unroll
        for (int i = 0; i < 4; i++)
            af[i] = *(const v8s*)(Al + (wm + i * 16 + lm) * LDA + quad * 8);
        #pragma unroll
        for (int j = 0; j < 4; j++)
            bfr[j] = *(const v8s*)(Bl + (wn + j * 16 + lm) * LDA + quad * 8);
        #pragma unroll
        for (int i = 0; i < 4; i++)
            #pragma unroll
            for (int j = 0; j < 4; j++)
                acc[i][j] = __builtin_amdgcn_mfma_f32_16x16x32_bf16(af[i], bfr[j], acc[i][j], 0, 0, 0);
    }
    #pragma unroll
    for (int i = 0; i < 4; i++) {
        #pragma unroll
        for (int r = 0; r < 4; r++) {
            int row = m0 + wm + i * 16 + quad * 4 + r;
            size_t base = ((size_t)b * Nn + row) * Hh + n0 + wn + lm;
            #pragma unroll
            for (int j = 0; j < 4; j++)
                out[base + j * 16] = acc[i][j][r];
        }
    }
}

// CSR build: per-batch exclusive scan of deg -> rowptr (+ cursor copy).
__global__ __launch_bounds__(1024) void csr_scan(const int* __restrict__ deg,
                                                 int* __restrict__ rowptr,
                                                 int* __restrict__ cursor) {
    int b = blockIdx.x;
    int tid = threadIdx.x;
    int ln = tid & 63, wv = tid >> 6;
    __shared__ int wsum[16];
    int d0 = deg[b * NUP + 2 * tid], d1 = deg[b * NUP + 2 * tid + 1];
    int s = d0 + d1;
    int x = s;
    #pragma unroll
    for (int off = 1; off < 64; off <<= 1) {
        int y = __shfl_up(x, off);
        if (ln >= off) x += y;
    }
    if (ln == 63) wsum[wv] = x;
    __syncthreads();
    int base = 0;
    for (int w = 0; w < wv; w++) base += wsum[w];
    int excl = base + x - s;
    rowptr[b * (NUP + 1) + 2 * tid] = excl;
    rowptr[b * (NUP + 1) + 2 * tid + 1] = excl + d0;
    cursor[b * NUP + 2 * tid] = excl;
    cursor[b * NUP + 2 * tid + 1] = excl + d0;
    if (tid == 1023) rowptr[b * (NUP + 1) + NUP] = excl + s;
}

// CSR build: fill edge array (src = batch-local down node id).
__global__ void csr_fill(const int* __restrict__ mask, const int* __restrict__ knn,
                         const int* __restrict__ up_local, int* __restrict__ cursor,
                         int* __restrict__ edges) {
    int b = blockIdx.y;
    int i = blockIdx.x * 256 + threadIdx.x;
    int g = b * Nn + i;
    if (mask[g]) return;
    #pragma unroll
    for (int m = 0; m < MM; m++) {
        int un = knn[g * MM + m];
        int slot = atomicAdd(&cursor[b * NUP + up_local[b * Nn + un]], 1);
        edges[b * EPB + slot] = i;
    }
}

// Kernel D: gather-max. One wave per up node; lanes own 4 cols (float4).
__global__ void gather_kernel(const float4* __restrict__ upc, const int* __restrict__ rowptr,
                              const int* __restrict__ edges, float* __restrict__ out) {
    int b = blockIdx.y;
    int u = blockIdx.x * 4 + (threadIdx.x >> 6);
    int lane = threadIdx.x & 63;
    int node = __float_as_int(upc[b * NUP + u].w);
    int start = rowptr[b * (NUP + 1) + u];
    int end   = rowptr[b * (NUP + 1) + u + 1];
    const int* eb = edges + b * EPB;
    size_t rowbase = (size_t)b * Nn * Hh + (size_t)(lane << 2);
    float4 a0 = make_float4(-3.4e38f, -3.4e38f, -3.4e38f, -3.4e38f);
    float4 a1 = a0;
    int e = start;
    for (; e + 2 <= end; e += 2) {
        int s0 = eb[e], s1 = eb[e + 1];
        float4 v0 = *(const float4*)(out + rowbase + (size_t)s0 * Hh);
        float4 v1 = *(const float4*)(out + rowbase + (size_t)s1 * Hh);
        a0.x = fmaxf(a0.x, v0.x); a0.y = fmaxf(a0.y, v0.y);
        a0.z = fmaxf(a0.z, v0.z); a0.w = fmaxf(a0.w, v0.w);
        a1.x = fmaxf(a1.x, v1.x); a1.y = fmaxf(a1.y, v1.y);
        a1.z = fmaxf(a1.z, v1.z); a1.w = fmaxf(a1.w, v1.w);
    }
    if (e < end) {
        int s0 = eb[e];
        float4 v0 = *(const float4*)(out + rowbase + (size_t)s0 * Hh);
        a0.x = fmaxf(a0.x, v0.x); a0.y = fmaxf(a0.y, v0.y);
        a0.z = fmaxf(a0.z, v0.z); a0.w = fmaxf(a0.w, v0.w);
    }
    float4 r;
    r.x = fmaxf(a0.x, a1.x); r.y = fmaxf(a0.y, a1.y);
    r.z = fmaxf(a0.z, a1.z); r.w = fmaxf(a0.w, a1.w);
    if (start == end) r = make_float4(0.f, 0.f, 0.f, 0.f);
    *(float4*)(out + rowbase + (size_t)node * Hh) = r;
}

// Kernel E: zero down rows, write mask tail.
__global__ void finalize_kernel(const int* __restrict__ mask, float* __restrict__ out) {
    int b = blockIdx.y;
    int node = blockIdx.x * 4 + (threadIdx.x >> 6);
    int g = b * Nn + node;
    int lane = threadIdx.x & 63;
    bool up = mask[g] != 0;
    if (!up)
        *(float4*)(out + (size_t)g * Hh + (lane << 2)) = make_float4(0.f, 0.f, 0.f, 0.f);
    if (lane == 0) out[(size_t)Bb * Nn * Hh + g] = up ? 1.0f : 0.0f;
}

extern "C" void kernel_launch(void* const* d_in, const int* in_sizes, int n_in,
                              void* d_out, int out_size, void* d_ws, size_t ws_size,
                              hipStream_t stream) {
    const float* h    = (const float*)d_in[0];
    const float* sl   = (const float*)d_in[1];
    const float* sc   = (const float*)d_in[2];
    const float* W    = (const float*)d_in[3];
    const float* bias = (const float*)d_in[4];

    char* ws = (char*)d_ws;
    int* mask = (int*)ws;                 ws += (size_t)Bb * Nn * sizeof(int);
    int* knn  = (int*)ws;                 ws += (size_t)Bb * Nn * MM * sizeof(int);
    float4* upc = (float4*)ws;            ws += (size_t)Bb * NUP * sizeof(float4);
    unsigned short* Wt = (unsigned short*)ws; ws += (size_t)Hh * KP * sizeof(unsigned short);
    int* up_local = (int*)ws;             ws += (size_t)Bb * Nn * sizeof(int);
    int* deg = (int*)ws;                  ws += (size_t)Bb * NUP * sizeof(int);
    int* cursor = (int*)ws;               ws += (size_t)Bb * NUP * sizeof(int);
    int* rowptr = (int*)ws;               ws += (size_t)Bb * (NUP + 1) * sizeof(int);
    int* edges = (int*)ws;                ws += (size_t)Bb * EPB * sizeof(int);
    float4* upg = (float4*)ws;            ws += (size_t)Bb * NUP * sizeof(float4);
    int* cellptr = (int*)ws;              ws += (size_t)Bb * (NCELL + 1) * sizeof(int);
    float2* gridp = (float2*)ws;          ws += (size_t)Bb * sizeof(float2);
    float4* dord = (float4*)ws;           // B*NDOWN float4
    float* outf = (float*)d_out;

    dim3 blk(256);
    select_kernel<<<dim3(Bb), dim3(1024), 0, stream>>>(sc, sl, mask, upc, up_local, deg);
    prep_kernel<<<dim3(Bb), dim3(1024), 0, stream>>>(sl, mask, upc, upg, cellptr, gridp, dord);
    knn_wave<<<dim3(NDOWN / 64, Bb), dim3(64), 0, stream>>>(upg, cellptr, gridp, dord,
                                                            up_local, knn, deg);
    csr_scan<<<dim3(Bb), dim3(1024), 0, stream>>>(deg, rowptr, cursor);
    csr_fill<<<dim3(Nn / 256, Bb), blk, 0, stream>>>(mask, knn, up_local, cursor, edges);
    wt_kernel<<<dim3(Hh), blk, 0, stream>>>(W, bias, Wt);
    feat_mfma<<<dim3(Nn / 128, 2, Bb), blk, 0, stream>>>(h, sl, sc, Wt, outf);
    gather_kernel<<<dim3(NUP / 4, Bb), blk, 0, stream>>>(upc, rowptr, edges, outf);
    finalize_kernel<<<dim3(Nn / 4, Bb), blk, 0, stream>>>(mask, outf);
}

// Round 10
// 351.327 us; speedup vs baseline: 2.3342x; 1.3778x over previous
//
#include <hip/hip_runtime.h>

#define Bb 8
#define Nn 8192
#define Hh 256
#define NUP 2048
#define NDOWN (Nn - NUP)
#define MM 5
#define EPB (NDOWN * MM)   // edges per batch = 30720
#define NCX 16
#define NC2 256            // 16x16 2D cells
#define KP 288             // padded K for the feat GEMM (256 h + sl,score,1,pad)
#define LDA 36             // LDS row stride (bf16) for A/B tiles

typedef short v8s __attribute__((ext_vector_type(8)));
typedef float v4f __attribute__((ext_vector_type(4)));

#define INFKEY 0x7F800000FFFFFFFFull

// fp32 -> bf16 round-to-nearest-even
__device__ __forceinline__ unsigned short bfc(float f) {
    unsigned u = __float_as_uint(f);
    return (unsigned short)((u + 0x7FFFu + ((u >> 16) & 1u)) >> 16);
}

// Find the bin (descending order) where the kth-largest element lands.
template <int NB>
__device__ void find_kth_bin(const int* hist, int kth, int tid,
                             int* wsumA, int* res, int* out_bin, int* out_cntgt) {
    constexpr int PER = NB / 1024;
    int ln = tid & 63, wv = tid >> 6;
    int b0 = NB - 1 - PER * tid;
    int c0 = hist[b0];
    int c1 = (PER == 2) ? hist[b0 - 1] : 0;
    int tot = c0 + c1;
    int x = tot;
    #pragma unroll
    for (int off = 1; off < 64; off <<= 1) {
        int y = __shfl_up(x, off);
        if (ln >= off) x += y;
    }
    if (ln == 63) wsumA[wv] = x;
    __syncthreads();
    int wbase = 0;
    for (int w = 0; w < wv; w++) wbase += wsumA[w];
    int excl = wbase + x - tot;
    if (excl < kth && excl + c0 >= kth) { res[0] = b0; res[1] = excl; }
    else if (PER == 2 && excl + c0 < kth && excl + c0 + c1 >= kth) { res[0] = b0 - 1; res[1] = excl + c0; }
    __syncthreads();
    *out_bin = res[0];
    *out_cntgt = res[1];
}

// Kernel A: exact top-NUP selection via 3-level radix select, fused compaction
// + up_local inverse map + deg zeroing.
__global__ __launch_bounds__(1024) void select_kernel(
        const float* __restrict__ scores, const float* __restrict__ sl,
        int* __restrict__ mask, float4* __restrict__ upc,
        int* __restrict__ up_local, int* __restrict__ deg) {
    int b = blockIdx.x;
    int tid = threadIdx.x;
    int ln = tid & 63, wv = tid >> 6;
    __shared__ int hist[2048];
    __shared__ int wsumA[16], wsumB[16];
    __shared__ int res[2];
    __shared__ int sbase[2];
    const float* s = scores + (size_t)b * Nn;

    deg[b * NUP + tid] = 0;
    deg[b * NUP + 1024 + tid] = 0;

    hist[tid] = 0; hist[tid + 1024] = 0;
    __syncthreads();
    for (int t = tid; t < Nn; t += 1024)
        atomicAdd(&hist[__float_as_uint(s[t]) >> 21], 1);
    __syncthreads();
    int B1, gt1;
    find_kth_bin<2048>(hist, NUP, tid, wsumA, res, &B1, &gt1);
    int slots1 = NUP - gt1;

    hist[tid] = 0; hist[tid + 1024] = 0;
    __syncthreads();
    for (int t = tid; t < Nn; t += 1024) {
        unsigned u = __float_as_uint(s[t]);
        if ((int)(u >> 21) == B1) atomicAdd(&hist[(u >> 10) & 0x7FF], 1);
    }
    __syncthreads();
    int B2, gt2;
    find_kth_bin<2048>(hist, slots1, tid, wsumA, res, &B2, &gt2);
    int slots2 = slots1 - gt2;
    unsigned hi22 = ((unsigned)B1 << 11) | (unsigned)B2;

    hist[tid] = 0; hist[tid + 1024] = 0;
    __syncthreads();
    for (int t = tid; t < Nn; t += 1024) {
        unsigned u = __float_as_uint(s[t]);
        if ((u >> 10) == hi22) atomicAdd(&hist[u & 0x3FF], 1);
    }
    __syncthreads();
    int B3, gt3;
    find_kth_bin<1024>(hist, slots2, tid, wsumA, res, &B3, &gt3);
    int slots_eq = slots2 - gt3;
    unsigned T = (hi22 << 10) | (unsigned)B3;

    if (tid == 0) { sbase[0] = 0; sbase[1] = 0; }
    __syncthreads();
    for (int t0 = 0; t0 < Nn; t0 += 1024) {
        int node = t0 + tid;
        int g = b * Nn + node;
        unsigned u = __float_as_uint(s[node]);
        bool eq = (u == T);
        unsigned long long bal = __ballot(eq);
        unsigned long long lmask = (1ull << ln) - 1ull;
        int pre = __popcll(bal & lmask);
        if (ln == 0) wsumA[wv] = __popcll(bal);
        __syncthreads();
        int eqbase = sbase[0];
        for (int w = 0; w < wv; w++) eqbase += wsumA[w];
        bool up = (u > T) || (eq && (eqbase + pre) < slots_eq);
        unsigned long long bal2 = __ballot(up);
        int pre2 = __popcll(bal2 & lmask);
        if (ln == 0) wsumB[wv] = __popcll(bal2);
        __syncthreads();
        int upbase = sbase[1];
        for (int w = 0; w < wv; w++) upbase += wsumB[w];
        if (up) {
            float4 c;
            c.x = sl[(size_t)g * 3 + 0];
            c.y = sl[(size_t)g * 3 + 1];
            c.z = sl[(size_t)g * 3 + 2];
            c.w = __int_as_float(node);
            upc[b * NUP + upbase + pre2] = c;
            up_local[g] = upbase + pre2;
        }
        mask[g] = up ? 1 : 0;
        __syncthreads();
        if (tid == 0) {
            int se = 0, su = 0;
            for (int w = 0; w < 16; w++) { se += wsumA[w]; su += wsumB[w]; }
            sbase[0] += se; sbase[1] += su;
        }
        __syncthreads();
    }
}

// Kernel P: per-batch 2D spatial prep. Bucket ups into 16x16 (x,y) cells
// (counting sort -> upg/cellptr/grid params) and counting-sort downs by home
// cell -> dord.
__global__ __launch_bounds__(1024) void prep_kernel(
        const float* __restrict__ sl, const int* __restrict__ mask,
        const float4* __restrict__ upc, float4* __restrict__ upg,
        int* __restrict__ cellptr, float4* __restrict__ gridp,
        float4* __restrict__ dord) {
    int b = blockIdx.x;
    int tid = threadIdx.x;
    int ln = tid & 63, wv = tid >> 6;
    __shared__ float rnx[16], rxx[16], rny[16], rxy[16];
    __shared__ int hist[NC2], cur[NC2];
    __shared__ int cp[NC2 + 1];
    __shared__ float4 sgp;

    float4 u0 = upc[b * NUP + tid];
    float4 u1 = upc[b * NUP + 1024 + tid];
    float mnx = fminf(u0.x, u1.x), mxx = fmaxf(u0.x, u1.x);
    float mny = fminf(u0.y, u1.y), mxy = fmaxf(u0.y, u1.y);
    #pragma unroll
    for (int off = 32; off; off >>= 1) {
        mnx = fminf(mnx, __shfl_down(mnx, off));
        mxx = fmaxf(mxx, __shfl_down(mxx, off));
        mny = fminf(mny, __shfl_down(mny, off));
        mxy = fmaxf(mxy, __shfl_down(mxy, off));
    }
    if (ln == 0) { rnx[wv] = mnx; rxx[wv] = mxx; rny[wv] = mny; rxy[wv] = mxy; }
    if (tid < NC2) hist[tid] = 0;
    __syncthreads();
    if (tid == 0) {
        float ax = rnx[0], cx = rxx[0], ay = rny[0], cy = rxy[0];
        for (int w2 = 1; w2 < 16; w2++) {
            ax = fminf(ax, rnx[w2]); cx = fmaxf(cx, rxx[w2]);
            ay = fminf(ay, rny[w2]); cy = fmaxf(cy, rxy[w2]);
        }
        float wx = fmaxf(cx - ax, 1e-20f) * (1.0f / NCX) * 1.0000002f;
        float wy = fmaxf(cy - ay, 1e-20f) * (1.0f / NCX) * 1.0000002f;
        sgp = make_float4(ax, wx, ay, wy);
    }
    __syncthreads();
    float4 gp = sgp;
    int cx0 = min(NCX - 1, max(0, (int)((u0.x - gp.x) / gp.y)));
    int cy0 = min(NCX - 1, max(0, (int)((u0.y - gp.z) / gp.w)));
    int cx1 = min(NCX - 1, max(0, (int)((u1.x - gp.x) / gp.y)));
    int cy1 = min(NCX - 1, max(0, (int)((u1.y - gp.z) / gp.w)));
    int cid0 = cy0 * NCX + cx0, cid1 = cy1 * NCX + cx1;
    atomicAdd(&hist[cid0], 1);
    atomicAdd(&hist[cid1], 1);
    __syncthreads();
    if (wv == 0) {  // 64 lanes x 4 bins: prefix over 256 bins
        int h0 = hist[4 * ln], h1 = hist[4 * ln + 1], h2 = hist[4 * ln + 2], h3 = hist[4 * ln + 3];
        int s = h0 + h1 + h2 + h3; int x = s;
        #pragma unroll
        for (int off = 1; off < 64; off <<= 1) {
            int y = __shfl_up(x, off);
            if (ln >= off) x += y;
        }
        int excl = x - s;
        cp[4 * ln] = excl; cp[4 * ln + 1] = excl + h0;
        cp[4 * ln + 2] = excl + h0 + h1; cp[4 * ln + 3] = excl + h0 + h1 + h2;
        if (ln == 63) cp[NC2] = x;
    }
    __syncthreads();
    if (tid < NC2) cur[tid] = cp[tid];
    if (tid <= NC2) cellptr[b * (NC2 + 1) + tid] = cp[tid];
    if (tid == 0) gridp[b] = gp;
    __syncthreads();
    int s0 = atomicAdd(&cur[cid0], 1); upg[b * NUP + s0] = u0;
    int s1 = atomicAdd(&cur[cid1], 1); upg[b * NUP + s1] = u1;

    // ---- downs: counting-sort by home 2D cell
    __syncthreads();
    if (tid < NC2) hist[tid] = 0;
    __syncthreads();
    for (int t = tid; t < Nn; t += 1024) {
        int g = b * Nn + t;
        if (!mask[g]) {
            float x = sl[(size_t)g * 3 + 0];
            float y = sl[(size_t)g * 3 + 1];
            int cx = min(NCX - 1, max(0, (int)((x - gp.x) / gp.y)));
            int cy = min(NCX - 1, max(0, (int)((y - gp.z) / gp.w)));
            atomicAdd(&hist[cy * NCX + cx], 1);
        }
    }
    __syncthreads();
    if (wv == 0) {
        int h0 = hist[4 * ln], h1 = hist[4 * ln + 1], h2 = hist[4 * ln + 2], h3 = hist[4 * ln + 3];
        int s = h0 + h1 + h2 + h3; int x = s;
        #pragma unroll
        for (int off = 1; off < 64; off <<= 1) {
            int y = __shfl_up(x, off);
            if (ln >= off) x += y;
        }
        int excl = x - s;
        cp[4 * ln] = excl; cp[4 * ln + 1] = excl + h0;
        cp[4 * ln + 2] = excl + h0 + h1; cp[4 * ln + 3] = excl + h0 + h1 + h2;
    }
    __syncthreads();
    if (tid < NC2) cur[tid] = cp[tid];
    __syncthreads();
    for (int t = tid; t < Nn; t += 1024) {
        int g = b * Nn + t;
        if (!mask[g]) {
            float x = sl[(size_t)g * 3 + 0];
            float y = sl[(size_t)g * 3 + 1];
            float z = sl[(size_t)g * 3 + 2];
            int cx = min(NCX - 1, max(0, (int)((x - gp.x) / gp.y)));
            int cy = min(NCX - 1, max(0, (int)((y - gp.z) / gp.w)));
            int slot = atomicAdd(&cur[cy * NCX + cx], 1);
            float4 e; e.x = x; e.y = y; e.z = z; e.w = __int_as_float(t);
            dord[b * NDOWN + slot] = e;
        }
    }
}

// Kernel C: exact 5-NN, 2D-cell pruned, high-occupancy. 256-thread block =
// 64 cell-sorted downs x 4 candidate-subset threads. Phase A: scan block
// home-rect +1 ring, expand until every down has >=5 found. Phase B: T =
// per-down merged 5th-best (upper bound), block-max -> radius; scan target
// rect minus scanned rect (disjoint). u64 (d2<<32|id) keys = exact (d2,idx).
__global__ __launch_bounds__(256) void knn2d(
        const float4* __restrict__ upg, const int* __restrict__ cellptr,
        const float4* __restrict__ gridp, const float4* __restrict__ dord,
        const int* __restrict__ up_local, int* __restrict__ knn,
        int* __restrict__ deg) {
    int b = blockIdx.y;
    int tid = threadIdx.x;
    int sub = tid >> 6, dn = tid & 63;
    __shared__ int cp[NC2 + 1];
    __shared__ float4 stage[256];
    __shared__ unsigned long long part[20 * 64];  // [(l*5+m)*64 + dn]
    __shared__ int fc[4][64];
    __shared__ float redf[8];
    __shared__ int flag;
    for (int k = tid; k <= NC2; k += 256) cp[k] = cellptr[b * (NC2 + 1) + k];
    float4 gp = gridp[b];
    float4 d = dord[b * NDOWN + blockIdx.x * 64 + dn];
    float xd = d.x, yd = d.y, zd = d.z;
    int node = __float_as_int(d.w);
    int cx = min(NCX - 1, max(0, (int)((xd - gp.x) / gp.y)));
    int cy = min(NCX - 1, max(0, (int)((yd - gp.z) / gp.w)));

    unsigned long long bd[MM];
    #pragma unroll
    for (int m = 0; m < MM; m++) bd[m] = INFKEY;

    auto ins = [&](unsigned long long* L, unsigned long long cand) {
        #pragma unroll
        for (int m = 0; m < MM; m++) {
            bool lt = cand < L[m];
            unsigned long long lo = lt ? cand : L[m];
            unsigned long long hi = lt ? L[m] : cand;
            L[m] = lo; cand = hi;
        }
    };
    // scan contiguous cell range [c0..c1]; block-uniform args
    auto scanCells = [&](int c0, int c1) {
        int ps = cp[c0], pe = cp[c1 + 1];
        for (int p0 = ps; p0 < pe; p0 += 256) {
            int cnt = min(256, pe - p0);
            __syncthreads();
            if (tid < cnt) stage[tid] = upg[b * NUP + p0 + tid];
            __syncthreads();
            for (int j = sub; j < cnt; j += 4) {
                float4 c = stage[j];
                float dx = c.x - xd, dy = c.y - yd, dz = c.z - zd;
                float d2 = fmaf(dx, dx, fmaf(dy, dy, dz * dz));
                ins(bd, ((unsigned long long)__float_as_uint(d2) << 32) |
                        (unsigned long long)(unsigned)__float_as_int(c.w));
            }
        }
    };

    // block home-cell extent
    int v = cx;
    #pragma unroll
    for (int off = 32; off; off >>= 1) v = min(v, __shfl_xor(v, off));
    int cxLo = v;  v = cx;
    #pragma unroll
    for (int off = 32; off; off >>= 1) v = max(v, __shfl_xor(v, off));
    int cxHi = v;  v = cy;
    #pragma unroll
    for (int off = 32; off; off >>= 1) v = min(v, __shfl_xor(v, off));
    int cyLo = v;  v = cy;
    #pragma unroll
    for (int off = 32; off; off >>= 1) v = max(v, __shfl_xor(v, off));
    int cyHi = v;
    // (waves are sub-uniform, every wave's dn spans 0..63 -> same result; no LDS needed)

    int sxL = max(0, cxLo - 1), sxH = min(NCX - 1, cxHi + 1);
    int syL = max(0, cyLo - 1), syH = min(NCX - 1, cyHi + 1);
    for (int ry = syL; ry <= syH; ry++) scanCells(ry * NCX + sxL, ry * NCX + sxH);

    // expansion until every down has >=5 found (block-wide)
    while (true) {
        __syncthreads();
        if (tid == 0) flag = 0;
        int f = 0;
        #pragma unroll
        for (int m = 0; m < MM; m++) f += (bd[m] != INFKEY) ? 1 : 0;
        fc[sub][dn] = f;
        __syncthreads();
        if (sub == 0) {
            int tot = fc[0][dn] + fc[1][dn] + fc[2][dn] + fc[3][dn];
            if (tot < MM) atomicAdd(&flag, 1);
        }
        __syncthreads();
        if (flag == 0) break;
        if (sxL == 0 && sxH == NCX - 1 && syL == 0 && syH == NCX - 1) break;
        int nxL = max(0, sxL - 1), nxH = min(NCX - 1, sxH + 1);
        int nyL = max(0, syL - 1), nyH = min(NCX - 1, syH + 1);
        for (int ry = nyL; ry <= nyH; ry++) {
            if (ry < syL || ry > syH) scanCells(ry * NCX + nxL, ry * NCX + nxH);
            else {
                if (nxL < sxL) scanCells(ry * NCX + nxL, ry * NCX + sxL - 1);
                if (nxH > sxH) scanCells(ry * NCX + sxH + 1, ry * NCX + nxH);
            }
        }
        sxL = nxL; sxH = nxH; syL = nyL; syH = nyH;
    }

    // Phase B bound: merged 5th-best per down -> block max radius
    __syncthreads();
    #pragma unroll
    for (int m = 0; m < MM; m++) part[(sub * MM + m) * 64 + dn] = bd[m];
    __syncthreads();
    if (sub == 0) {
        unsigned long long fin[MM];
        #pragma unroll
        for (int m = 0; m < MM; m++) fin[m] = 0xFFFFFFFFFFFFFFFFull;
        #pragma unroll
        for (int l = 0; l < 4; l++)
            #pragma unroll
            for (int m = 0; m < MM; m++) ins(fin, part[(l * MM + m) * 64 + dn]);
        float T = __uint_as_float((unsigned)(fin[MM - 1] >> 32));
        float Tm = T, xl = xd, xh = xd, yl = yd, yh = yd;
        #pragma unroll
        for (int off = 32; off; off >>= 1) {
            Tm = fmaxf(Tm, __shfl_xor(Tm, off));
            xl = fminf(xl, __shfl_xor(xl, off));
            xh = fmaxf(xh, __shfl_xor(xh, off));
            yl = fminf(yl, __shfl_xor(yl, off));
            yh = fmaxf(yh, __shfl_xor(yh, off));
        }
        if (dn == 0) { redf[0] = Tm; redf[1] = xl; redf[2] = xh; redf[3] = yl; redf[4] = yh; }
    }
    __syncthreads();
    float r = sqrtf(redf[0]);
    int txL = min(NCX - 1, max(0, (int)((redf[1] - r - gp.x) / gp.y)));
    int txH = min(NCX - 1, max(0, (int)((redf[2] + r - gp.x) / gp.y)));
    int tyL = min(NCX - 1, max(0, (int)((redf[3] - r - gp.z) / gp.w)));
    int tyH = min(NCX - 1, max(0, (int)((redf[4] + r - gp.z) / gp.w)));
    for (int ry = tyL; ry <= tyH; ry++) {
        if (ry < syL || ry > syH) {
            if (txL <= txH) scanCells(ry * NCX + txL, ry * NCX + txH);
        } else {
            int xb = min(txH, sxL - 1);
            if (txL <= xb) scanCells(ry * NCX + txL, ry * NCX + xb);
            int xa = max(txL, sxH + 1);
            if (xa <= txH) scanCells(ry * NCX + xa, ry * NCX + txH);
        }
    }

    // final merge + outputs
    __syncthreads();
    #pragma unroll
    for (int m = 0; m < MM; m++) part[(sub * MM + m) * 64 + dn] = bd[m];
    __syncthreads();
    if (sub == 0) {
        unsigned long long fin[MM];
        #pragma unroll
        for (int m = 0; m < MM; m++) fin[m] = 0xFFFFFFFFFFFFFFFFull;
        #pragma unroll
        for (int l = 0; l < 4; l++)
            #pragma unroll
            for (int m = 0; m < MM; m++) ins(fin, part[(l * MM + m) * 64 + dn]);
        int g = b * Nn + node;
        #pragma unroll
        for (int m = 0; m < MM; m++) {
            int nid = (int)(unsigned)(fin[m] & 0xFFFFFFFFull);
            knn[g * MM + m] = nid;
            atomicAdd(&deg[b * NUP + up_local[b * Nn + nid]], 1);
        }
    }
}

// Kernel W: Wt[n][k] = bf16 of W-ext^T.
__global__ void wt_kernel(const float* __restrict__ W, const float* __restrict__ bias,
                          unsigned short* __restrict__ Wt) {
    int n = blockIdx.x;
    int k = threadIdx.x;
    Wt[n * KP + k] = bfc(W[(size_t)k * Hh + n]);
    if (k < KP - 256) {
        int kk = 256 + k;
        unsigned short v = 0;
        if (kk < 260)       v = bfc(W[(size_t)kk * Hh + n]);
        else if (kk == 260) v = bfc(bias[n]);
        Wt[n * KP + kk] = v;
    }
}

// Kernel B: feat GEMM via bf16 MFMA. C[128m x 128n] per block, 4 waves of 64x64.
__global__ void feat_mfma(const float* __restrict__ h, const float* __restrict__ sl,
                          const float* __restrict__ sc, const unsigned short* __restrict__ Wt,
                          float* __restrict__ out) {
    int b = blockIdx.z;
    int m0 = blockIdx.x * 128;
    int n0 = blockIdx.y * 128;
    int tid = threadIdx.x;
    __shared__ unsigned short Al[128 * LDA];
    __shared__ unsigned short Bl[128 * LDA];
    int wid = tid >> 6, lane = tid & 63;
    int wm = (wid & 1) * 64, wn = (wid >> 1) * 64;
    int lm = lane & 15, quad = lane >> 4;
    v4f acc[4][4];
    #pragma unroll
    for (int i = 0; i < 4; i++)
        #pragma unroll
        for (int j = 0; j < 4; j++)
            acc[i][j] = (v4f){0.f, 0.f, 0.f, 0.f};
    const float* Ab = h + ((size_t)b * Nn + m0) * Hh;
    for (int t = 0; t < 9; t++) {
        int k0 = t * 32;
        __syncthreads();
        if (t < 8) {
            #pragma unroll
            for (int q = 0; q < 4; q++) {
                int e = q * 256 + tid;
                int row = e >> 3, kq = e & 7;
                float4 v = *(const float4*)(Ab + (size_t)row * Hh + k0 + kq * 4);
                ushort4 o = make_ushort4(bfc(v.x), bfc(v.y), bfc(v.z), bfc(v.w));
                *(ushort4*)(Al + row * LDA + kq * 4) = o;
            }
        } else if (tid < 128) {
            int row = tid;
            int g = b * Nn + m0 + row;
            unsigned short r[32];
            #pragma unroll
            for (int k = 0; k < 32; k++) r[k] = 0;
            r[0] = bfc(sl[(size_t)g * 3 + 0]);
            r[1] = bfc(sl[(size_t)g * 3 + 1]);
            r[2] = bfc(sl[(size_t)g * 3 + 2]);
            r[3] = bfc(sc[g]);
            r[4] = 0x3F80;  // 1.0 (bias column)
            #pragma unroll
            for (int q = 0; q < 8; q++)
                *(ushort4*)(Al + row * LDA + q * 4) =
                    make_ushort4(r[q * 4], r[q * 4 + 1], r[q * 4 + 2], r[q * 4 + 3]);
        }
        #pragma unroll
        for (int q = 0; q < 4; q++) {
            int e = q * 256 + tid;
            int n = e >> 3, kq = e & 7;
            ushort4 v = *(const ushort4*)(Wt + (size_t)(n0 + n) * KP + k0 + kq * 4);
            *(ushort4*)(Bl + n * LDA + kq * 4) = v;
        }
        __syncthreads();
        v8s af[4], bfr[4];
        #pragma unroll
        for (int i = 0; i < 4; i++)
            af[i] = *(const v8s*)(Al + (wm + i * 16 + lm) * LDA + quad * 8);
        #pragma unroll
        for (int j = 0; j < 4; j++)
            bfr[j] = *(const v8s*)(Bl + (wn + j * 16 + lm) * LDA + quad * 8);
        #pragma unroll
        for (int i = 0; i < 4; i++)
            #pragma unroll
            for (int j = 0; j < 4; j++)
                acc[i][j] = __builtin_amdgcn_mfma_f32_16x16x32_bf16(af[i], bfr[j], acc[i][j], 0, 0, 0);
    }
    #pragma unroll
    for (int i = 0; i < 4; i++) {
        #pragma unroll
        for (int r = 0; r < 4; r++) {
            int row = m0 + wm + i * 16 + quad * 4 + r;
            size_t base = ((size_t)b * Nn + row) * Hh + n0 + wn + lm;
            #pragma unroll
            for (int j = 0; j < 4; j++)
                out[base + j * 16] = acc[i][j][r];
        }
    }
}

// CSR build: per-batch exclusive scan of deg -> rowptr (+ cursor copy).
__global__ __launch_bounds__(1024) void csr_scan(const int* __restrict__ deg,
                                                 int* __restrict__ rowptr,
                                                 int* __restrict__ cursor) {
    int b = blockIdx.x;
    int tid = threadIdx.x;
    int ln = tid & 63, wv = tid >> 6;
    __shared__ int wsum[16];
    int d0 = deg[b * NUP + 2 * tid], d1 = deg[b * NUP + 2 * tid + 1];
    int s = d0 + d1;
    int x = s;
    #pragma unroll
    for (int off = 1; off < 64; off <<= 1) {
        int y = __shfl_up(x, off);
        if (ln >= off) x += y;
    }
    if (ln == 63) wsum[wv] = x;
    __syncthreads();
    int base = 0;
    for (int w = 0; w < wv; w++) base += wsum[w];
    int excl = base + x - s;
    rowptr[b * (NUP + 1) + 2 * tid] = excl;
    rowptr[b * (NUP + 1) + 2 * tid + 1] = excl + d0;
    cursor[b * NUP + 2 * tid] = excl;
    cursor[b * NUP + 2 * tid + 1] = excl + d0;
    if (tid == 1023) rowptr[b * (NUP + 1) + NUP] = excl + s;
}

// CSR build: fill edge array (src = batch-local down node id).
__global__ void csr_fill(const int* __restrict__ mask, const int* __restrict__ knn,
                         const int* __restrict__ up_local, int* __restrict__ cursor,
                         int* __restrict__ edges) {
    int b = blockIdx.y;
    int i = blockIdx.x * 256 + threadIdx.x;
    int g = b * Nn + i;
    if (mask[g]) return;
    #pragma unroll
    for (int m = 0; m < MM; m++) {
        int un = knn[g * MM + m];
        int slot = atomicAdd(&cursor[b * NUP + up_local[b * Nn + un]], 1);
        edges[b * EPB + slot] = i;
    }
}

// Kernel D: gather-max. One wave per up node; lanes own 4 cols (float4).
__global__ void gather_kernel(const float4* __restrict__ upc, const int* __restrict__ rowptr,
                              const int* __restrict__ edges, float* __restrict__ out) {
    int b = blockIdx.y;
    int u = blockIdx.x * 4 + (threadIdx.x >> 6);
    int lane = threadIdx.x & 63;
    int node = __float_as_int(upc[b * NUP + u].w);
    int start = rowptr[b * (NUP + 1) + u];
    int end   = rowptr[b * (NUP + 1) + u + 1];
    const int* eb = edges + b * EPB;
    size_t rowbase = (size_t)b * Nn * Hh + (size_t)(lane << 2);
    float4 a0 = make_float4(-3.4e38f, -3.4e38f, -3.4e38f, -3.4e38f);
    float4 a1 = a0;
    int e = start;
    for (; e + 2 <= end; e += 2) {
        int s0 = eb[e], s1 = eb[e + 1];
        float4 v0 = *(const float4*)(out + rowbase + (size_t)s0 * Hh);
        float4 v1 = *(const float4*)(out + rowbase + (size_t)s1 * Hh);
        a0.x = fmaxf(a0.x, v0.x); a0.y = fmaxf(a0.y, v0.y);
        a0.z = fmaxf(a0.z, v0.z); a0.w = fmaxf(a0.w, v0.w);
        a1.x = fmaxf(a1.x, v1.x); a1.y = fmaxf(a1.y, v1.y);
        a1.z = fmaxf(a1.z, v1.z); a1.w = fmaxf(a1.w, v1.w);
    }
    if (e < end) {
        int s0 = eb[e];
        float4 v0 = *(const float4*)(out + rowbase + (size_t)s0 * Hh);
        a0.x = fmaxf(a0.x, v0.x); a0.y = fmaxf(a0.y, v0.y);
        a0.z = fmaxf(a0.z, v0.z); a0.w = fmaxf(a0.w, v0.w);
    }
    float4 r;
    r.x = fmaxf(a0.x, a1.x); r.y = fmaxf(a0.y, a1.y);
    r.z = fmaxf(a0.z, a1.z); r.w = fmaxf(a0.w, a1.w);
    if (start == end) r = make_float4(0.f, 0.f, 0.f, 0.f);
    *(float4*)(out + rowbase + (size_t)node * Hh) = r;
}

// Kernel E: zero down rows, write mask tail.
__global__ void finalize_kernel(const int* __restrict__ mask, float* __restrict__ out) {
    int b = blockIdx.y;
    int node = blockIdx.x * 4 + (threadIdx.x >> 6);
    int g = b * Nn + node;
    int lane = threadIdx.x & 63;
    bool up = mask[g] != 0;
    if (!up)
        *(float4*)(out + (size_t)g * Hh + (lane << 2)) = make_float4(0.f, 0.f, 0.f, 0.f);
    if (lane == 0) out[(size_t)Bb * Nn * Hh + g] = up ? 1.0f : 0.0f;
}

extern "C" void kernel_launch(void* const* d_in, const int* in_sizes, int n_in,
                              void* d_out, int out_size, void* d_ws, size_t ws_size,
                              hipStream_t stream) {
    const float* h    = (const float*)d_in[0];
    const float* sl   = (const float*)d_in[1];
    const float* sc   = (const float*)d_in[2];
    const float* W    = (const float*)d_in[3];
    const float* bias = (const float*)d_in[4];

    char* ws = (char*)d_ws;
    int* mask = (int*)ws;                 ws += (size_t)Bb * Nn * sizeof(int);
    int* knn  = (int*)ws;                 ws += (size_t)Bb * Nn * MM * sizeof(int);
    float4* upc = (float4*)ws;            ws += (size_t)Bb * NUP * sizeof(float4);
    unsigned short* Wt = (unsigned short*)ws; ws += (size_t)Hh * KP * sizeof(unsigned short);
    int* up_local = (int*)ws;             ws += (size_t)Bb * Nn * sizeof(int);
    int* deg = (int*)ws;                  ws += (size_t)Bb * NUP * sizeof(int);
    int* cursor = (int*)ws;               ws += (size_t)Bb * NUP * sizeof(int);
    int* rowptr = (int*)ws;               ws += (size_t)Bb * (NUP + 1) * sizeof(int);
    int* edges = (int*)ws;                ws += (size_t)Bb * EPB * sizeof(int);
    float4* upg = (float4*)ws;            ws += (size_t)Bb * NUP * sizeof(float4);
    int* cellptr = (int*)ws;              ws += (size_t)Bb * (NC2 + 1) * sizeof(int);
    float4* gridp = (float4*)ws;          ws += (size_t)Bb * sizeof(float4);
    float4* dord = (float4*)ws;           // B*NDOWN float4
    float* outf = (float*)d_out;

    dim3 blk(256);
    select_kernel<<<dim3(Bb), dim3(1024), 0, stream>>>(sc, sl, mask, upc, up_local, deg);
    prep_kernel<<<dim3(Bb), dim3(1024), 0, stream>>>(sl, mask, upc, upg, cellptr, gridp, dord);
    knn2d<<<dim3(NDOWN / 64, Bb), blk, 0, stream>>>(upg, cellptr, gridp, dord,
                                                    up_local, knn, deg);
    csr_scan<<<dim3(Bb), dim3(1024), 0, stream>>>(deg, rowptr, cursor);
    csr_fill<<<dim3(Nn / 256, Bb), blk, 0, stream>>>(mask, knn, up_local, cursor, edges);
    wt_kernel<<<dim3(Hh), blk, 0, stream>>>(W, bias, Wt);
    feat_mfma<<<dim3(Nn / 128, 2, Bb), blk, 0, stream>>>(h, sl, sc, Wt, outf);
    gather_kernel<<<dim3(NUP / 4, Bb), blk, 0, stream>>>(upc, rowptr, edges, outf);
    finalize_kernel<<<dim3(Nn / 4, Bb), blk, 0, stream>>>(mask, outf);
}